// Round 4
// baseline (442.212 us; speedup 1.0000x reference)
//
#include <hip/hip_runtime.h>
#include <math.h>

#define NN 8192
#define DIN 256
#define DOUT 128
#define HS 8208      // hT row stride (bf16 elems), 16416 B (16B-aligned)
#define PSTRIDE 136  // p_lds row stride (bf16 elems) = 272 B: bank-spread + 16B-aligned

typedef __attribute__((ext_vector_type(8))) short short8;
typedef __attribute__((ext_vector_type(8))) __bf16 bf16x8;
typedef __attribute__((ext_vector_type(4))) float f32x4;
typedef __attribute__((ext_vector_type(4))) unsigned short ushort4v;
typedef __attribute__((ext_vector_type(4))) int int4v;

__device__ __forceinline__ bf16x8 as_bf(short8 s) { return __builtin_bit_cast(bf16x8, s); }
__device__ __forceinline__ unsigned short f2bf(float f) {
  union { float ff; unsigned int i; } v; v.ff = f;
  unsigned int r = v.i + 0x7FFFu + ((v.i >> 16) & 1u);
  return (unsigned short)(r >> 16);
}

// ---- Kernel 0: one-time W -> bf16 conversion + a2key init --------------------
// Removes the 512x-redundant per-block W conversion from k1 (32K f2bf per block)
// and replaces the hipMemsetAsync graph node for the atomicMax identity.
__global__ __launch_bounds__(256) void k0_prep(const float* __restrict__ W,
                                               unsigned short* __restrict__ Wbf,
                                               unsigned int* __restrict__ a2key)
{
  const int i = (blockIdx.x * 256 + threadIdx.x) * 4;   // 32 blocks cover 32768 elems
  f32x4 v = *(const f32x4*)(W + i);
  ushort4v o;
#pragma unroll
  for (int t = 0; t < 4; ++t) o[t] = f2bf(v[t]);
  *(ushort4v*)(Wbf + i) = o;
  if (blockIdx.x == 0 && threadIdx.x == 0) *a2key = 0u;  // keys are always > 0
}

// ---- Kernel 1 (MFMA): hT (bf16, [d][j] padded); a1, a2; global max(a2) ------
// grid 512 x block 64 (1 wave): 16 rows x 128 dims via 8 C-frags of 16x16x32.
// Verified layout: A[m=lane&15][k=q*8+t]; B[k=q*8+t][n=lane&15]; D: col=lane&15, row=q*4+reg.
// After the xor-butterfly over {1,2,4,8}, ALL 16 lanes of each q-group hold the
// full dot products s1[r]/s2[r] -> wave-max of a2 is 2 shuffles + 1 atomicMax
// on a monotonic uint key (replaces the old single-block max kernel).
__global__ __launch_bounds__(64) void k1_h(
    const float* __restrict__ feat, const unsigned short* __restrict__ Wbf,
    const float* __restrict__ bias, const float* __restrict__ w1,
    const float* __restrict__ b1, const float* __restrict__ w2,
    const float* __restrict__ b2,
    unsigned short* __restrict__ hT,
    float* __restrict__ a1, float* __restrict__ a2,
    unsigned int* __restrict__ a2key)
{
  const int lane = threadIdx.x;
  const int m = lane & 15, q = lane >> 4;
  const int r0 = blockIdx.x * 16;

  f32x4 acc[8] = {};
  const float* fRow = feat + (size_t)(r0 + m) * DIN + q * 8;
#pragma unroll
  for (int k0 = 0; k0 < DIN; k0 += 32) {
    short8 af;
#pragma unroll
    for (int t = 0; t < 8; ++t) af[t] = (short)f2bf(fRow[k0 + t]);
#pragma unroll
    for (int g = 0; g < 8; ++g) {
      const short8 wf = *(const short8*)(Wbf + (size_t)(g * 16 + m) * DIN + k0 + q * 8);
      acc[g] = __builtin_amdgcn_mfma_f32_16x16x32_bf16(as_bf(af), as_bf(wf), acc[g], 0, 0, 0);
    }
  }
  float s1[4] = {0.f, 0.f, 0.f, 0.f}, s2[4] = {0.f, 0.f, 0.f, 0.f};
#pragma unroll
  for (int g = 0; g < 8; ++g) {
    const int d = g * 16 + m;
    const float bv = bias[d];
    const float w1v = w1[d];
    const float w2v = w2[d];
    ushort4v st;
#pragma unroll
    for (int r = 0; r < 4; ++r) {
      float v = acc[g][r] + bv;
      st[r] = f2bf(v);
      s1[r] += v * w1v;
      s2[r] += v * w2v;
    }
    *(ushort4v*)(hT + (size_t)d * HS + r0 + q * 4) = st;  // bf16 hT for k2 B-frags
  }
#pragma unroll
  for (int r = 0; r < 4; ++r) {
    s1[r] += __shfl_xor(s1[r], 1, 64); s2[r] += __shfl_xor(s2[r], 1, 64);
    s1[r] += __shfl_xor(s1[r], 2, 64); s2[r] += __shfl_xor(s2[r], 2, 64);
    s1[r] += __shfl_xor(s1[r], 4, 64); s2[r] += __shfl_xor(s2[r], 4, 64);
    s1[r] += __shfl_xor(s1[r], 8, 64); s2[r] += __shfl_xor(s2[r], 8, 64);
  }
  const float bb1 = b1[0], bb2 = b2[0];
  if (m == 0) {
#pragma unroll
    for (int r = 0; r < 4; ++r) {
      a1[r0 + q * 4 + r] = s1[r] + bb1;
      a2[r0 + q * 4 + r] = s2[r] + bb2;
    }
  }
  // block-local max of the 16 a2 values -> one device-scope atomic per block
  float am = fmaxf(fmaxf(s2[0], s2[1]), fmaxf(s2[2], s2[3])) + bb2;
  am = fmaxf(am, __shfl_xor(am, 16, 64));
  am = fmaxf(am, __shfl_xor(am, 32, 64));
  if (lane == 0) {
    unsigned int u = __float_as_uint(am);
    unsigned int key = (u & 0x80000000u) ? ~u : (u | 0x80000000u);  // order-preserving
    atomicMax(a2key, key);
  }
}

// ---- Kernel 2 (MFMA, 2-stage pipelined): out = softmax-normalized P @ H ------
// Block: 16 rows x 128 d, 256 thr (4 waves). Wave w owns d-tiles {w*32, w*32+16}.
// Per tile t: issue B-frags(t) -> exp(tile t+1 from regs issued @ t-1) ->
// issue adj(t+2) -> MFMA(t) -> ds_write p(t+1) -> barrier. vmcnt ordering:
// expify waits only on the OLDER adj/a2 loads; hT loads drain under the VALU.
// Little's law: 1 pending 8KB adj batch/block x 2 blocks/CU over ~900cy HBM
// latency sustains ~43 GB/s/CU > the 24.6 GB/s/CU fair share -> saturating.
__global__ __launch_bounds__(256) void GATLayer_46024869544127_kernel(
    const int* __restrict__ adj, const unsigned short* __restrict__ hT,
    const float* __restrict__ a1, const float* __restrict__ a2,
    const unsigned int* __restrict__ a2key, float* __restrict__ out)
{
  __shared__ unsigned short p_lds[2][16][PSTRIDE];
  __shared__ float zred[4][16];

  const int tid = threadIdx.x;
  const int lane = tid & 63;
  const int w = tid >> 6;                 // wave 0..3
  const int r0 = blockIdx.x * 16;
  const int NT = NN / 128;

  // phase-A mapping: thread -> (row, 8-j group)
  const int arow = tid & 15;              // 0..15
  const int ajg = tid >> 4;               // 0..15
  const float a1i = a1[r0 + arow];
  // decode global max(a2); fold M[i] = leaky(a1[i] + a2max) to a local scalar.
  // leaky is monotonic -> mi is an upper bound of the row's leaky values:
  // valid softmax shift (exp args <= 0, adj=0 entries underflow to exactly 0).
  const unsigned int kraw = *a2key;
  const unsigned int mu = (kraw & 0x80000000u) ? (kraw ^ 0x80000000u) : ~kraw;
  const float yi = a1i + __uint_as_float(mu);
  const float mi = fmaxf(yi, 0.01f * yi);

  float zpart = 0.f;
  const int* adjRow = adj + (size_t)(r0 + arow) * NN + ajg * 8;
  const float* a2p = a2 + ajg * 8;

  // phase-B mapping
  const int m = lane & 15, q = lane >> 4;
  const int d0 = w * 32;
  const unsigned short* hT0 = hT + (size_t)(d0 + m) * HS + q * 8;
  const unsigned short* hT1 = hT + (size_t)(d0 + 16 + m) * HS + q * 8;

  f32x4 acc0 = {}, acc1 = {};

  // pending regs for the NEXT tile's exp (named scalars -> stay in VGPRs)
  int4v pd0, pd1;
  f32x4 pv0, pv1;

  auto issue = [&](int j0) {
    pd0 = *(const int4v*)(adjRow + j0);
    pd1 = *(const int4v*)(adjRow + j0 + 4);
    pv0 = *(const f32x4*)(a2p + j0);
    pv1 = *(const f32x4*)(a2p + j0 + 4);
  };
  auto expify = [&](ushort4v& o0, ushort4v& o1) {
#pragma unroll
    for (int t = 0; t < 4; ++t) {
      float y = a1i + pv0[t];
      float ly = fmaxf(y, 0.01f * y);
      float pv = (pd0[t] > 0) ? __expf(ly - mi) : 0.f;
      zpart += pv;
      o0[t] = f2bf(pv);
    }
#pragma unroll
    for (int t = 0; t < 4; ++t) {
      float y = a1i + pv1[t];
      float ly = fmaxf(y, 0.01f * y);
      float pv = (pd1[t] > 0) ? __expf(ly - mi) : 0.f;
      zpart += pv;
      o1[t] = f2bf(pv);
    }
  };

  // prologue: tile 0 -> LDS buf0 (synchronous, once); issue tile 1 loads
  {
    issue(0);
    ushort4v o0, o1;
    expify(o0, o1);
    *(ushort4v*)&p_lds[0][arow][ajg * 8] = o0;
    *(ushort4v*)&p_lds[0][arow][ajg * 8 + 4] = o1;
  }
  issue(128);
  __syncthreads();

  for (int jt = 0; jt < NT; ++jt) {
    const int cur = jt & 1;
    const int j0 = jt * 128;
    const bool hasN = (jt + 1) < NT;

    // B-frags for THIS tile: issue first; consumed by the MFMAs below.
    const short8 b00 = *(const short8*)(hT0 + j0);
    const short8 b01 = *(const short8*)(hT1 + j0);
    const short8 b10 = *(const short8*)(hT0 + j0 + 32);
    const short8 b11 = *(const short8*)(hT1 + j0 + 32);
    const short8 b20 = *(const short8*)(hT0 + j0 + 64);
    const short8 b21 = *(const short8*)(hT1 + j0 + 64);
    const short8 b30 = *(const short8*)(hT0 + j0 + 96);
    const short8 b31 = *(const short8*)(hT1 + j0 + 96);

    // exp tile jt+1 from pending regs (issued one full tile ago)
    ushort4v o0, o1;
    if (hasN) expify(o0, o1);

    // issue adj/a2 loads for tile jt+2 (consumed next iteration)
    if (jt + 2 < NT) issue((jt + 2) * 128);

    // A-frags from LDS + 8 MFMAs over tile jt
    const short8 af0 = *(const short8*)&p_lds[cur][m][q * 8];
    const short8 af1 = *(const short8*)&p_lds[cur][m][32 + q * 8];
    const short8 af2 = *(const short8*)&p_lds[cur][m][64 + q * 8];
    const short8 af3 = *(const short8*)&p_lds[cur][m][96 + q * 8];
    acc0 = __builtin_amdgcn_mfma_f32_16x16x32_bf16(as_bf(af0), as_bf(b00), acc0, 0, 0, 0);
    acc1 = __builtin_amdgcn_mfma_f32_16x16x32_bf16(as_bf(af0), as_bf(b01), acc1, 0, 0, 0);
    acc0 = __builtin_amdgcn_mfma_f32_16x16x32_bf16(as_bf(af1), as_bf(b10), acc0, 0, 0, 0);
    acc1 = __builtin_amdgcn_mfma_f32_16x16x32_bf16(as_bf(af1), as_bf(b11), acc1, 0, 0, 0);
    acc0 = __builtin_amdgcn_mfma_f32_16x16x32_bf16(as_bf(af2), as_bf(b20), acc0, 0, 0, 0);
    acc1 = __builtin_amdgcn_mfma_f32_16x16x32_bf16(as_bf(af2), as_bf(b21), acc1, 0, 0, 0);
    acc0 = __builtin_amdgcn_mfma_f32_16x16x32_bf16(as_bf(af3), as_bf(b30), acc0, 0, 0, 0);
    acc1 = __builtin_amdgcn_mfma_f32_16x16x32_bf16(as_bf(af3), as_bf(b31), acc1, 0, 0, 0);

    // publish p(jt+1) into the other LDS buffer
    if (hasN) {
      *(ushort4v*)&p_lds[cur ^ 1][arow][ajg * 8] = o0;
      *(ushort4v*)&p_lds[cur ^ 1][arow][ajg * 8 + 4] = o1;
    }
    __syncthreads();
  }

  // Z reduction: sum zpart over the 16 j-groups for each row
  float zw = zpart;
  zw += __shfl_xor(zw, 16, 64);
  zw += __shfl_xor(zw, 32, 64);
  if (lane < 16) zred[w][arow] = zw;
  __syncthreads();

#pragma unroll
  for (int r = 0; r < 4; ++r) {
    const int row = q * 4 + r;
    const float Z = zred[0][row] + zred[1][row] + zred[2][row] + zred[3][row];
    const float inv = (Z > 0.f) ? 1.f / Z : 0.f;
    out[(size_t)(r0 + row) * DOUT + d0 + m] = acc0[r] * inv;
    out[(size_t)(r0 + row) * DOUT + d0 + 16 + m] = acc1[r] * inv;
  }
}

extern "C" void kernel_launch(void* const* d_in, const int* in_sizes, int n_in,
                              void* d_out, int out_size, void* d_ws, size_t ws_size,
                              hipStream_t stream) {
  const float* feat = (const float*)d_in[0];
  const int* adj = (const int*)d_in[1];
  const float* W = (const float*)d_in[2];
  const float* b = (const float*)d_in[3];
  const float* w1 = (const float*)d_in[4];
  const float* b1 = (const float*)d_in[5];
  const float* w2 = (const float*)d_in[6];
  const float* b2 = (const float*)d_in[7];
  float* out = (float*)d_out;

  char* ws = (char*)d_ws;
  unsigned short* hT = (unsigned short*)ws;                 // 128*8208*2 B = 2,101,248
  float* a1 = (float*)(ws + (size_t)DOUT * HS * 2);
  float* a2 = a1 + NN;
  unsigned int* a2key = (unsigned int*)(a2 + NN);
  unsigned short* Wbf = (unsigned short*)(a2key + 4);       // 64 KB, 16B-aligned

  k0_prep<<<DOUT * DIN / (256 * 4), 256, 0, stream>>>(W, Wbf, a2key);
  k1_h<<<512, 64, 0, stream>>>(feat, Wbf, b, w1, b1, w2, b2, hT, a1, a2, a2key);
  GATLayer_46024869544127_kernel<<<NN / 16, 256, 0, stream>>>(adj, hT, a1, a2, a2key, out);
}

// Round 5
// 440.947 us; speedup vs baseline: 1.0029x; 1.0029x over previous
//
#include <hip/hip_runtime.h>
#include <math.h>

#define NN 8192
#define DIN 256
#define DOUT 128
#define HS 8208      // hT row stride (bf16 elems), 16416 B (16B-aligned)
#define PSTRIDE 136  // p_lds row stride (bf16 elems) = 272 B: bank-spread + 16B-aligned

// Raw barrier WITHOUT the vmcnt(0) drain that __syncthreads() emits: only LDS
// (lgkmcnt) must be visible across the barrier; global prefetches stay in
// flight (T4 — the m97 "barrier drain" stall was the modeled 3x gap here).
#define BAR_LDS() do { asm volatile("s_waitcnt lgkmcnt(0)" ::: "memory"); \
                       __builtin_amdgcn_s_barrier(); } while (0)

typedef __attribute__((ext_vector_type(8))) short short8;
typedef __attribute__((ext_vector_type(8))) __bf16 bf16x8;
typedef __attribute__((ext_vector_type(4))) float f32x4;
typedef __attribute__((ext_vector_type(4))) unsigned short ushort4v;
typedef __attribute__((ext_vector_type(4))) int int4v;

__device__ __forceinline__ bf16x8 as_bf(short8 s) { return __builtin_bit_cast(bf16x8, s); }
__device__ __forceinline__ unsigned short f2bf(float f) {
  union { float ff; unsigned int i; } v; v.ff = f;
  unsigned int r = v.i + 0x7FFFu + ((v.i >> 16) & 1u);
  return (unsigned short)(r >> 16);
}

// ---- Kernel 0: one-time W -> bf16 conversion + a2key init --------------------
__global__ __launch_bounds__(256) void k0_prep(const float* __restrict__ W,
                                               unsigned short* __restrict__ Wbf,
                                               unsigned int* __restrict__ a2key)
{
  const int i = (blockIdx.x * 256 + threadIdx.x) * 4;   // 32 blocks cover 32768 elems
  f32x4 v = *(const f32x4*)(W + i);
  ushort4v o;
#pragma unroll
  for (int t = 0; t < 4; ++t) o[t] = f2bf(v[t]);
  *(ushort4v*)(Wbf + i) = o;
  if (blockIdx.x == 0 && threadIdx.x == 0) *a2key = 0u;  // keys are always > 0
}

// ---- Kernel 1 (MFMA): hT (bf16, [d][j] padded); a1, a2; global max(a2) ------
// grid 512 x block 64 (1 wave): 16 rows x 128 dims via 8 C-frags of 16x16x32.
// Verified layout: A[m=lane&15][k=q*8+t]; B[k=q*8+t][n=lane&15]; D: col=lane&15, row=q*4+reg.
__global__ __launch_bounds__(64) void k1_h(
    const float* __restrict__ feat, const unsigned short* __restrict__ Wbf,
    const float* __restrict__ bias, const float* __restrict__ w1,
    const float* __restrict__ b1, const float* __restrict__ w2,
    const float* __restrict__ b2,
    unsigned short* __restrict__ hT,
    float* __restrict__ a1, float* __restrict__ a2,
    unsigned int* __restrict__ a2key)
{
  const int lane = threadIdx.x;
  const int m = lane & 15, q = lane >> 4;
  const int r0 = blockIdx.x * 16;

  f32x4 acc[8] = {};
  const float* fRow = feat + (size_t)(r0 + m) * DIN + q * 8;
#pragma unroll
  for (int k0 = 0; k0 < DIN; k0 += 32) {
    short8 af;
#pragma unroll
    for (int t = 0; t < 8; ++t) af[t] = (short)f2bf(fRow[k0 + t]);
#pragma unroll
    for (int g = 0; g < 8; ++g) {
      const short8 wf = *(const short8*)(Wbf + (size_t)(g * 16 + m) * DIN + k0 + q * 8);
      acc[g] = __builtin_amdgcn_mfma_f32_16x16x32_bf16(as_bf(af), as_bf(wf), acc[g], 0, 0, 0);
    }
  }
  float s1[4] = {0.f, 0.f, 0.f, 0.f}, s2[4] = {0.f, 0.f, 0.f, 0.f};
#pragma unroll
  for (int g = 0; g < 8; ++g) {
    const int d = g * 16 + m;
    const float bv = bias[d];
    const float w1v = w1[d];
    const float w2v = w2[d];
    ushort4v st;
#pragma unroll
    for (int r = 0; r < 4; ++r) {
      float v = acc[g][r] + bv;
      st[r] = f2bf(v);
      s1[r] += v * w1v;
      s2[r] += v * w2v;
    }
    *(ushort4v*)(hT + (size_t)d * HS + r0 + q * 4) = st;  // bf16 hT for k2 B-frags
  }
#pragma unroll
  for (int r = 0; r < 4; ++r) {
    s1[r] += __shfl_xor(s1[r], 1, 64); s2[r] += __shfl_xor(s2[r], 1, 64);
    s1[r] += __shfl_xor(s1[r], 2, 64); s2[r] += __shfl_xor(s2[r], 2, 64);
    s1[r] += __shfl_xor(s1[r], 4, 64); s2[r] += __shfl_xor(s2[r], 4, 64);
    s1[r] += __shfl_xor(s1[r], 8, 64); s2[r] += __shfl_xor(s2[r], 8, 64);
  }
  const float bb1 = b1[0], bb2 = b2[0];
  if (m == 0) {
#pragma unroll
    for (int r = 0; r < 4; ++r) {
      a1[r0 + q * 4 + r] = s1[r] + bb1;
      a2[r0 + q * 4 + r] = s2[r] + bb2;
    }
  }
  // block-local max of the 16 a2 values -> one device-scope atomic per block
  float am = fmaxf(fmaxf(s2[0], s2[1]), fmaxf(s2[2], s2[3])) + bb2;
  am = fmaxf(am, __shfl_xor(am, 16, 64));
  am = fmaxf(am, __shfl_xor(am, 32, 64));
  if (lane == 0) {
    unsigned int u = __float_as_uint(am);
    unsigned int key = (u & 0x80000000u) ? ~u : (u | 0x80000000u);  // order-preserving
    atomicMax(a2key, key);
  }
}

// ---- Kernel 2 (MFMA, 2-stage pipelined, counted-wait barriers) ---------------
// Block: 16 rows x 128 d, 256 thr (4 waves). Wave w owns d-tiles {w*32, w*32+16}.
// Per tile t: issue B-frags(t) -> exp(tile t+1 from regs issued @ t-1) ->
// issue adj(t+2) -> MFMA(t) -> ds_write p(t+1) -> BAR_LDS. The raw barrier
// does NOT drain vmcnt, so adj/a2/hT prefetches genuinely span barriers;
// the compiler inserts counted vmcnt waits at each register use.
__global__ __launch_bounds__(256) void GATLayer_46024869544127_kernel(
    const int* __restrict__ adj, const unsigned short* __restrict__ hT,
    const float* __restrict__ a1, const float* __restrict__ a2,
    const unsigned int* __restrict__ a2key, float* __restrict__ out)
{
  __shared__ unsigned short p_lds[2][16][PSTRIDE];
  __shared__ float zred[4][16];

  const int tid = threadIdx.x;
  const int lane = tid & 63;
  const int w = tid >> 6;                 // wave 0..3
  const int r0 = blockIdx.x * 16;
  const int NT = NN / 128;

  // phase-A mapping: thread -> (row, 8-j group)
  const int arow = tid & 15;              // 0..15
  const int ajg = tid >> 4;               // 0..15
  const float a1i = a1[r0 + arow];
  // decode global max(a2); fold M[i] = leaky(a1[i] + a2max) to a local scalar.
  const unsigned int kraw = *a2key;
  const unsigned int mu = (kraw & 0x80000000u) ? (kraw ^ 0x80000000u) : ~kraw;
  const float yi = a1i + __uint_as_float(mu);
  const float mi = fmaxf(yi, 0.01f * yi);

  float zpart = 0.f;
  const int* adjRow = adj + (size_t)(r0 + arow) * NN + ajg * 8;
  const float* a2p = a2 + ajg * 8;

  // phase-B mapping
  const int m = lane & 15, q = lane >> 4;
  const int d0 = w * 32;
  const unsigned short* hT0 = hT + (size_t)(d0 + m) * HS + q * 8;
  const unsigned short* hT1 = hT + (size_t)(d0 + 16 + m) * HS + q * 8;

  f32x4 acc0 = {}, acc1 = {};

  // pending regs for the NEXT tile's exp (named scalars -> stay in VGPRs)
  int4v pd0, pd1;
  f32x4 pv0, pv1;

  auto issue = [&](int j0) {
    pd0 = *(const int4v*)(adjRow + j0);
    pd1 = *(const int4v*)(adjRow + j0 + 4);
    pv0 = *(const f32x4*)(a2p + j0);
    pv1 = *(const f32x4*)(a2p + j0 + 4);
  };
  auto expify = [&](ushort4v& o0, ushort4v& o1) {
#pragma unroll
    for (int t = 0; t < 4; ++t) {
      float y = a1i + pv0[t];
      float ly = fmaxf(y, 0.01f * y);
      float pv = (pd0[t] > 0) ? __expf(ly - mi) : 0.f;
      zpart += pv;
      o0[t] = f2bf(pv);
    }
#pragma unroll
    for (int t = 0; t < 4; ++t) {
      float y = a1i + pv1[t];
      float ly = fmaxf(y, 0.01f * y);
      float pv = (pd1[t] > 0) ? __expf(ly - mi) : 0.f;
      zpart += pv;
      o1[t] = f2bf(pv);
    }
  };

  // prologue: tile 0 -> LDS buf0 (synchronous, once); issue tile 1 loads
  {
    issue(0);
    ushort4v o0, o1;
    expify(o0, o1);
    *(ushort4v*)&p_lds[0][arow][ajg * 8] = o0;
    *(ushort4v*)&p_lds[0][arow][ajg * 8 + 4] = o1;
  }
  issue(128);
  BAR_LDS();

  for (int jt = 0; jt < NT; ++jt) {
    const int cur = jt & 1;
    const int j0 = jt * 128;
    const bool hasN = (jt + 1) < NT;

    // B-frags for THIS tile: issue first; consumed by the MFMAs below.
    const short8 b00 = *(const short8*)(hT0 + j0);
    const short8 b01 = *(const short8*)(hT1 + j0);
    const short8 b10 = *(const short8*)(hT0 + j0 + 32);
    const short8 b11 = *(const short8*)(hT1 + j0 + 32);
    const short8 b20 = *(const short8*)(hT0 + j0 + 64);
    const short8 b21 = *(const short8*)(hT1 + j0 + 64);
    const short8 b30 = *(const short8*)(hT0 + j0 + 96);
    const short8 b31 = *(const short8*)(hT1 + j0 + 96);

    // exp tile jt+1 from pending regs (issued one full tile ago)
    ushort4v o0, o1;
    if (hasN) expify(o0, o1);

    // issue adj/a2 loads for tile jt+2 (consumed next iteration)
    if (jt + 2 < NT) issue((jt + 2) * 128);

    // A-frags from LDS + 8 MFMAs over tile jt
    const short8 af0 = *(const short8*)&p_lds[cur][m][q * 8];
    const short8 af1 = *(const short8*)&p_lds[cur][m][32 + q * 8];
    const short8 af2 = *(const short8*)&p_lds[cur][m][64 + q * 8];
    const short8 af3 = *(const short8*)&p_lds[cur][m][96 + q * 8];
    acc0 = __builtin_amdgcn_mfma_f32_16x16x32_bf16(as_bf(af0), as_bf(b00), acc0, 0, 0, 0);
    acc1 = __builtin_amdgcn_mfma_f32_16x16x32_bf16(as_bf(af0), as_bf(b01), acc1, 0, 0, 0);
    acc0 = __builtin_amdgcn_mfma_f32_16x16x32_bf16(as_bf(af1), as_bf(b10), acc0, 0, 0, 0);
    acc1 = __builtin_amdgcn_mfma_f32_16x16x32_bf16(as_bf(af1), as_bf(b11), acc1, 0, 0, 0);
    acc0 = __builtin_amdgcn_mfma_f32_16x16x32_bf16(as_bf(af2), as_bf(b20), acc0, 0, 0, 0);
    acc1 = __builtin_amdgcn_mfma_f32_16x16x32_bf16(as_bf(af2), as_bf(b21), acc1, 0, 0, 0);
    acc0 = __builtin_amdgcn_mfma_f32_16x16x32_bf16(as_bf(af3), as_bf(b30), acc0, 0, 0, 0);
    acc1 = __builtin_amdgcn_mfma_f32_16x16x32_bf16(as_bf(af3), as_bf(b31), acc1, 0, 0, 0);

    // publish p(jt+1) into the other LDS buffer
    if (hasN) {
      *(ushort4v*)&p_lds[cur ^ 1][arow][ajg * 8] = o0;
      *(ushort4v*)&p_lds[cur ^ 1][arow][ajg * 8 + 4] = o1;
    }
    BAR_LDS();
  }

  // Z reduction: sum zpart over the 16 j-groups for each row
  float zw = zpart;
  zw += __shfl_xor(zw, 16, 64);
  zw += __shfl_xor(zw, 32, 64);
  if (lane < 16) zred[w][arow] = zw;
  __syncthreads();

#pragma unroll
  for (int r = 0; r < 4; ++r) {
    const int row = q * 4 + r;
    const float Z = zred[0][row] + zred[1][row] + zred[2][row] + zred[3][row];
    const float inv = (Z > 0.f) ? 1.f / Z : 0.f;
    out[(size_t)(r0 + row) * DOUT + d0 + m] = acc0[r] * inv;
    out[(size_t)(r0 + row) * DOUT + d0 + 16 + m] = acc1[r] * inv;
  }
}

extern "C" void kernel_launch(void* const* d_in, const int* in_sizes, int n_in,
                              void* d_out, int out_size, void* d_ws, size_t ws_size,
                              hipStream_t stream) {
  const float* feat = (const float*)d_in[0];
  const int* adj = (const int*)d_in[1];
  const float* W = (const float*)d_in[2];
  const float* b = (const float*)d_in[3];
  const float* w1 = (const float*)d_in[4];
  const float* b1 = (const float*)d_in[5];
  const float* w2 = (const float*)d_in[6];
  const float* b2 = (const float*)d_in[7];
  float* out = (float*)d_out;

  char* ws = (char*)d_ws;
  unsigned short* hT = (unsigned short*)ws;                 // 128*8208*2 B = 2,101,248
  float* a1 = (float*)(ws + (size_t)DOUT * HS * 2);
  float* a2 = a1 + NN;
  unsigned int* a2key = (unsigned int*)(a2 + NN);
  unsigned short* Wbf = (unsigned short*)(a2key + 4);       // 64 KB, 16B-aligned

  k0_prep<<<DOUT * DIN / (256 * 4), 256, 0, stream>>>(W, Wbf, a2key);
  k1_h<<<512, 64, 0, stream>>>(feat, Wbf, b, w1, b1, w2, b2, hT, a1, a2, a2key);
  GATLayer_46024869544127_kernel<<<NN / 16, 256, 0, stream>>>(adj, hT, a1, a2, a2key, out);
}